// Round 3
// baseline (297.136 us; speedup 1.0000x reference)
//
#include <hip/hip_runtime.h>

// RoIAlign via TF crop_and_resize. Fixed problem shapes:
//   featuremap (N=2, C=256, H=200, W=304) fp32
//   rois       (M=2048, 5) fp32  [batch_id, x1, y1, x2, y2]
//   out        (M, C, 7, 7) fp32
//
// R2: block = (8 channels) x (32 boxes), XCD-pinned channel groups (fetch
//     382->194 MB).
// R3: batch 7 outputs/thread/iter -> 28 gather loads in flight before the
//     first consume (was 4). Attacks the latency-bound plateau (no pipe
//     >30% busy at R2).
#define RA_C   256
#define RA_H   200
#define RA_W   304
#define RA_HW  (RA_H * RA_W)        // 60800
#define RA_CHW (RA_C * RA_HW)       // 15564800
#define CROPN  7
#define CROP2  (CROPN * CROPN)      // 49
#define OUT_M  (RA_C * CROP2)       // 12544 floats per box
#define BC     8                    // channels per block
#define BM     32                   // boxes per block
#define PER_BLK (BM * BC * CROP2)   // 12544 elements per block
#define BATCH  7                    // outputs per thread per outer iter

__global__ __launch_bounds__(256) void roialign_kernel(
    const float* __restrict__ fm, const float* __restrict__ rois,
    const float* __restrict__ scale_p, float* __restrict__ out)
{
    __shared__ int   s_offT[BM][CROPN], s_offB[BM][CROPN];   // yt*W, yb*W
    __shared__ float s_ylerp[BM][CROPN], s_vy[BM][CROPN];
    __shared__ int   s_xl[BM][CROPN], s_xr[BM][CROPN];
    __shared__ float s_xlerp[BM][CROPN], s_vx[BM][CROPN];
    __shared__ int   s_imgbase[BM];

    const int t = threadIdx.x;

    // --- block -> (channel group, box group) with XCD pinning ---
    const int bid   = blockIdx.x;
    const int numBG = gridDim.x >> 5;          // M / BM
    const int xcd   = bid & 7;
    const int r     = bid >> 3;                // [0, 4*numBG)
    const int cgl   = r / numBG;               // [0, 4)
    const int bg    = r - cgl * numBG;         // [0, numBG)
    const int c0    = (xcd * 4 + cgl) * BC;    // first channel of group
    const int m0    = bg * BM;                 // first box of group

    // --- geometry for the BM boxes: BM*14 = 448 tasks over 256 threads ---
    for (int task = t; task < BM * 2 * CROPN; task += 256) {
        // Replicate the reference's fp32 arithmetic exactly (no contraction)
        // so validity comparisons (y>=0, y<=H-1) match numpy bit-for-bit.
        #pragma clang fp contract(off)
        {
            const int mm  = task / (2 * CROPN);
            const int k14 = task - mm * (2 * CROPN);
            const int axis = (k14 >= CROPN) ? 1 : 0;   // 0 = y, 1 = x
            const int k = axis ? (k14 - CROPN) : k14;
            const float scale = scale_p[0];
            const float* rr = rois + (size_t)(m0 + mm) * 5;
            if (k14 == 0) s_imgbase[mm] = (int)rr[0] * RA_CHW;
            float lo, hi, szm1;
            if (axis == 0) { lo = rr[2] * scale; hi = rr[4] * scale; szm1 = (float)(RA_H - 1); }
            else           { lo = rr[1] * scale; hi = rr[3] * scale; szm1 = (float)(RA_W - 1); }
            float sp   = (hi - lo) / 7.0f;
            float n0   = (lo + sp * 0.5f - 0.5f) / szm1;
            float nsz  = sp * 6.0f / szm1;
            float b2   = n0 + nsz;
            float d    = (b2 - n0) * szm1 / 6.0f;
            float coord = n0 * szm1 + (float)k * d;
            float fl = floorf(coord);
            float ce = ceilf(coord);
            float lerp = coord - fl;
            int lo_i = (int)fminf(fmaxf(fl, 0.0f), szm1);
            int hi_i = (int)fminf(fmaxf(ce, 0.0f), szm1);
            float valid = (coord >= 0.0f && coord <= szm1) ? 1.0f : 0.0f;
            if (axis == 0) {
                s_offT[mm][k] = lo_i * RA_W; s_offB[mm][k] = hi_i * RA_W;
                s_ylerp[mm][k] = lerp; s_vy[mm][k] = valid;
            } else {
                s_xl[mm][k] = lo_i; s_xr[mm][k] = hi_i;
                s_xlerp[mm][k] = lerp; s_vx[mm][k] = valid;
            }
        }
    }
    __syncthreads();

    // --- main sweep: 49 elements/thread = 7 outer x 7 batched ---
    // All 28 gather loads of a batch are issued before the first consume,
    // giving ~28 outstanding loads/wave instead of 4 (latency hiding).
    for (int outer = 0; outer < CROP2 / BATCH; ++outer) {
        const int e_base = t + outer * (BATCH * 256);
        float tl[BATCH], tr[BATCH], bl[BATCH], br[BATCH];
        float xw[BATCH], yw[BATCH], vv[BATCH];
        float* op[BATCH];
        #pragma unroll
        for (int q = 0; q < BATCH; ++q) {
            const int e   = e_base + q * 256;
            const int mm  = e / (BC * CROP2);
            const int rem = e - mm * (BC * CROP2);
            const int cc  = rem / CROP2;
            const int ij  = rem - cc * CROP2;
            const int i   = ij / CROPN;
            const int j   = ij - i * CROPN;
            const float* __restrict__ p =
                fm + (size_t)s_imgbase[mm] + (size_t)(c0 + cc) * RA_HW;
            const int ot = s_offT[mm][i], ob = s_offB[mm][i];
            const int xl = s_xl[mm][j],  xr = s_xr[mm][j];
            xw[q] = s_xlerp[mm][j];
            yw[q] = s_ylerp[mm][i];
            vv[q] = s_vy[mm][i] * s_vx[mm][j];
            tl[q] = p[ot + xl];
            tr[q] = p[ot + xr];
            bl[q] = p[ob + xl];
            br[q] = p[ob + xr];
            op[q] = out + (size_t)(m0 + mm) * OUT_M + (size_t)(c0 + cc) * CROP2 + ij;
        }
        #pragma unroll
        for (int q = 0; q < BATCH; ++q) {
            float top = tl[q] + (tr[q] - tl[q]) * xw[q];
            float bot = bl[q] + (br[q] - bl[q]) * xw[q];
            *op[q] = (top + (bot - top) * yw[q]) * vv[q];
        }
    }
}

extern "C" void kernel_launch(void* const* d_in, const int* in_sizes, int n_in,
                              void* d_out, int out_size, void* d_ws, size_t ws_size,
                              hipStream_t stream) {
    const float* fm    = (const float*)d_in[0];
    const float* rois  = (const float*)d_in[1];
    const float* scale = (const float*)d_in[2];
    float* out = (float*)d_out;
    const int M = in_sizes[1] / 5;             // 2048
    const int numBG = M / BM;                  // 64
    roialign_kernel<<<dim3(32 * numBG), dim3(256), 0, stream>>>(fm, rois, scale, out);
}

// Round 4
// 273.360 us; speedup vs baseline: 1.0870x; 1.0870x over previous
//
#include <hip/hip_runtime.h>

// RoIAlign via TF crop_and_resize. Fixed problem shapes:
//   featuremap (N=2, C=256, H=200, W=304) fp32
//   rois       (M=2048, 5) fp32  [batch_id, x1, y1, x2, y2]
//   out        (M, C, 7, 7) fp32
//
// R2: XCD-pinned channel groups (fetch 382->194 MB).
// R4: thread owns (box, sample); geometry held in REGISTERS (one LDS read in
//     prologue), 8-channel unrolled loop issues 32 structurally independent
//     gather loads (addresses = 4 fixed ints + cc*RA_HW). R3's compiler-
//     serialized batching (VGPR=40) is replaced by a dependence-free batch.
#define RA_C   256
#define RA_H   200
#define RA_W   304
#define RA_HW  (RA_H * RA_W)        // 60800
#define RA_CHW (RA_C * RA_HW)       // 15564800
#define CROPN  7
#define CROP2  (CROPN * CROPN)      // 49
#define OUT_M  (RA_C * CROP2)       // 12544 floats per box
#define BC     8                    // channels per block (one cg)
#define BM     4                    // boxes per block (64 lanes each)

__global__ __launch_bounds__(256) void roialign_kernel(
    const float* __restrict__ fm, const float* __restrict__ rois,
    const float* __restrict__ scale_p, float* __restrict__ out)
{
    __shared__ int   s_offT[BM][CROPN], s_offB[BM][CROPN];   // yt*W, yb*W
    __shared__ float s_ylerp[BM][CROPN], s_vy[BM][CROPN];
    __shared__ int   s_xl[BM][CROPN], s_xr[BM][CROPN];
    __shared__ float s_xlerp[BM][CROPN], s_vx[BM][CROPN];
    __shared__ int   s_imgbase[BM];

    const int t = threadIdx.x;

    // --- block -> (channel group, box group) with XCD pinning ---
    const int bid   = blockIdx.x;
    const int numBG = gridDim.x >> 5;          // M / BM
    const int xcd   = bid & 7;
    const int r     = bid >> 3;                // [0, 4*numBG)
    const int cgl   = r / numBG;               // [0, 4)
    const int bg    = r - cgl * numBG;         // [0, numBG)
    const int c0    = (xcd * 4 + cgl) * BC;    // first channel of group
    const int m0    = bg * BM;                 // first box of group

    // --- geometry for BM boxes: BM*14 = 56 tasks on threads 0..55 ---
    if (t < BM * 2 * CROPN) {
        // Replicate the reference's fp32 arithmetic exactly (no contraction)
        // so validity comparisons (y>=0, y<=H-1) match numpy bit-for-bit.
        #pragma clang fp contract(off)
        {
            const int mm  = t / (2 * CROPN);
            const int k14 = t - mm * (2 * CROPN);
            const int axis = (k14 >= CROPN) ? 1 : 0;   // 0 = y, 1 = x
            const int k = axis ? (k14 - CROPN) : k14;
            const float scale = scale_p[0];
            const float* rr = rois + (size_t)(m0 + mm) * 5;
            if (k14 == 0) s_imgbase[mm] = (int)rr[0] * RA_CHW;
            float lo, hi, szm1;
            if (axis == 0) { lo = rr[2] * scale; hi = rr[4] * scale; szm1 = (float)(RA_H - 1); }
            else           { lo = rr[1] * scale; hi = rr[3] * scale; szm1 = (float)(RA_W - 1); }
            float sp   = (hi - lo) / 7.0f;
            float n0   = (lo + sp * 0.5f - 0.5f) / szm1;
            float nsz  = sp * 6.0f / szm1;
            float b2   = n0 + nsz;
            float d    = (b2 - n0) * szm1 / 6.0f;
            float coord = n0 * szm1 + (float)k * d;
            float fl = floorf(coord);
            float ce = ceilf(coord);
            float lerp = coord - fl;
            int lo_i = (int)fminf(fmaxf(fl, 0.0f), szm1);
            int hi_i = (int)fminf(fmaxf(ce, 0.0f), szm1);
            float valid = (coord >= 0.0f && coord <= szm1) ? 1.0f : 0.0f;
            if (axis == 0) {
                s_offT[mm][k] = lo_i * RA_W; s_offB[mm][k] = hi_i * RA_W;
                s_ylerp[mm][k] = lerp; s_vy[mm][k] = valid;
            } else {
                s_xl[mm][k] = lo_i; s_xr[mm][k] = hi_i;
                s_xlerp[mm][k] = lerp; s_vx[mm][k] = valid;
            }
        }
    }
    __syncthreads();

    // --- thread = (box mm, sample ij); loop-invariant geometry in regs ---
    const int mm  = t >> 6;                    // 0..3
    const int ij  = t & 63;                    // 0..63 (49 active)
    const int ijc = (ij < CROP2) ? ij : (CROP2 - 1);  // clamp: lanes 49..63 broadcast
    const int i   = ijc / CROPN;
    const int j   = ijc - i * CROPN;

    const float* __restrict__ img = fm + s_imgbase[mm] + (size_t)c0 * RA_HW;
    const int aTL = s_offT[mm][i] + s_xl[mm][j];
    const int aTR = s_offT[mm][i] + s_xr[mm][j];
    const int aBL = s_offB[mm][i] + s_xl[mm][j];
    const int aBR = s_offB[mm][i] + s_xr[mm][j];
    const float xw = s_xlerp[mm][j];
    const float yw = s_ylerp[mm][i];
    const float vv = s_vy[mm][i] * s_vx[mm][j];

    // 32 structurally independent gather loads, then consume.
    float tl[BC], tr[BC], bl[BC], br[BC];
    #pragma unroll
    for (int cc = 0; cc < BC; ++cc) {
        const float* __restrict__ p = img + (size_t)cc * RA_HW;
        tl[cc] = p[aTL];
        tr[cc] = p[aTR];
        bl[cc] = p[aBL];
        br[cc] = p[aBR];
    }
    if (ij < CROP2) {
        float* __restrict__ op =
            out + (size_t)(m0 + mm) * OUT_M + (size_t)c0 * CROP2 + ij;
        #pragma unroll
        for (int cc = 0; cc < BC; ++cc) {
            float top = tl[cc] + (tr[cc] - tl[cc]) * xw;
            float bot = bl[cc] + (br[cc] - bl[cc]) * xw;
            op[cc * CROP2] = (top + (bot - top) * yw) * vv;
        }
    }
}

extern "C" void kernel_launch(void* const* d_in, const int* in_sizes, int n_in,
                              void* d_out, int out_size, void* d_ws, size_t ws_size,
                              hipStream_t stream) {
    const float* fm    = (const float*)d_in[0];
    const float* rois  = (const float*)d_in[1];
    const float* scale = (const float*)d_in[2];
    float* out = (float*)d_out;
    const int M = in_sizes[1] / 5;             // 2048
    const int numBG = M / BM;                  // 512
    roialign_kernel<<<dim3(32 * numBG), dim3(256), 0, stream>>>(fm, rois, scale, out);
}